// Round 4
// baseline (536.067 us; speedup 1.0000x reference)
//
#include <hip/hip_runtime.h>
#include <stdint.h>

#define N_TOK 8192
#define C_DIM 1024
#define H_DIM 3072
#define N_EXP 8
#define N_ASSIGN (N_TOK * 2)

typedef __attribute__((ext_vector_type(8))) short short8;
typedef __attribute__((ext_vector_type(4))) float f32x4;

__device__ __forceinline__ unsigned short f2bf(float f) {
    union { float f; uint32_t u; } v; v.f = f;
    uint32_t r = (v.u + 0x7FFFu + ((v.u >> 16) & 1u)) >> 16;
    return (unsigned short)r;
}

#define GLDS16(SRC, DST) __builtin_amdgcn_global_load_lds( \
    (const __attribute__((address_space(1))) void*)(SRC),  \
    (__attribute__((address_space(3))) void*)(DST), 16, 0, 0)

// ---------------- transpose + fp32->bf16 convert: out[col][row] = in[row][col], per expert (grid.z)
__global__ void transpose_bf16_kernel(const float* __restrict__ in, unsigned short* __restrict__ out,
                                      int rows, int cols) {
    __shared__ float tile[32][33];
    int e = blockIdx.z;
    const float* ip = in + (size_t)e * rows * cols;
    unsigned short* op = out + (size_t)e * rows * cols;
    int col0 = blockIdx.x * 32;
    int row0 = blockIdx.y * 32;
    int tx = threadIdx.x, ty = threadIdx.y;
    tile[ty][tx] = ip[(size_t)(row0 + ty) * cols + col0 + tx];
    __syncthreads();
    op[(size_t)(col0 + ty) * rows + row0 + tx] = f2bf(tile[tx][ty]);
}

// ---------------- router: logits = x @ Wr, softmax, top-2 (lowest-index ties), renorm; pi/cnt stats
__global__ __launch_bounds__(256) void router_kernel(const float* __restrict__ x, const float* __restrict__ Wr,
                                                     int2* __restrict__ idx2, float2* __restrict__ wgt2,
                                                     float* __restrict__ piAcc, int* __restrict__ cntAcc) {
    __shared__ float s_pi[8];
    __shared__ int s_cnt[8];
    int t = threadIdx.x;
    if (t < 8) { s_pi[t] = 0.f; s_cnt[t] = 0; }
    __syncthreads();
    int lane = t & 63;
    int wid = t >> 6;
    int gwv = blockIdx.x * 4 + wid;
    int nw = gridDim.x * 4;
    for (int n = gwv; n < N_TOK; n += nw) {
        float acc[8];
#pragma unroll
        for (int e = 0; e < 8; e++) acc[e] = 0.f;
        const float* xr = x + (size_t)n * C_DIM;
#pragma unroll
        for (int j = 0; j < 16; j++) {
            int k = lane + 64 * j;
            float xv = xr[k];
            const float4* wr4 = (const float4*)(Wr + (size_t)k * 8);
            float4 a = wr4[0], b = wr4[1];
            acc[0] += xv * a.x; acc[1] += xv * a.y; acc[2] += xv * a.z; acc[3] += xv * a.w;
            acc[4] += xv * b.x; acc[5] += xv * b.y; acc[6] += xv * b.z; acc[7] += xv * b.w;
        }
#pragma unroll
        for (int off = 1; off < 64; off <<= 1) {
#pragma unroll
            for (int e = 0; e < 8; e++) acc[e] += __shfl_xor(acc[e], off, 64);
        }
        float m = acc[0];
#pragma unroll
        for (int e = 1; e < 8; e++) m = fmaxf(m, acc[e]);
        float p[8]; float s = 0.f;
#pragma unroll
        for (int e = 0; e < 8; e++) { p[e] = __expf(acc[e] - m); s += p[e]; }
        float inv = 1.f / s;
#pragma unroll
        for (int e = 0; e < 8; e++) p[e] *= inv;
        int i0 = 0; float l0 = acc[0];
#pragma unroll
        for (int e = 1; e < 8; e++) if (acc[e] > l0) { l0 = acc[e]; i0 = e; }
        int i1 = -1; float l1 = -1e30f;
#pragma unroll
        for (int e = 0; e < 8; e++) if (e != i0 && acc[e] > l1) { l1 = acc[e]; i1 = e; }
        if (lane == 0) {
            float v0 = p[i0], v1 = p[i1];
            float rs = 1.f / (v0 + v1);
            idx2[n] = make_int2(i0, i1);
            wgt2[n] = make_float2(v0 * rs, v1 * rs);
            atomicAdd(&s_cnt[i0], 1);
            atomicAdd(&s_cnt[i1], 1);
#pragma unroll
            for (int e = 0; e < 8; e++) atomicAdd(&s_pi[e], p[e]);
        }
    }
    __syncthreads();
    if (t < 8) { atomicAdd(&piAcc[t], s_pi[t]); atomicAdd(&cntAcc[t], s_cnt[t]); }
}

// ---------------- offsets (exclusive scan of cnt) + aux loss
__global__ void finalize_router_kernel(const int* __restrict__ cnt, const float* __restrict__ pi,
                                       int* __restrict__ off, float* __restrict__ aux_out) {
    if (threadIdx.x == 0) {
        int o = 0;
        float dot = 0.f;
        for (int e = 0; e < 8; e++) {
            off[e] = o;
            o += cnt[e];
            dot += (float)cnt[e] * pi[e];
        }
        aux_out[0] = 0.01f * 8.f * dot / ((float)N_TOK * (float)N_TOK);
    }
}

// ---------------- scatter: build per-expert token/weight lists (block-aggregated cursors)
__global__ __launch_bounds__(256) void scatter_kernel(const int2* __restrict__ idx2, const float2* __restrict__ wgt2,
                                                      const int* __restrict__ off, int* __restrict__ cursor,
                                                      int* __restrict__ tok, float* __restrict__ gwArr) {
    __shared__ int lcnt[8], lbase[8];
    int t = threadIdx.x;
    if (t < 8) lcnt[t] = 0;
    __syncthreads();
    int a = blockIdx.x * 256 + t;
    int n = a >> 1, k = a & 1;
    int2 id = idx2[n];
    float2 w = wgt2[n];
    int e = k ? id.y : id.x;
    float wv = k ? w.y : w.x;
    int rank = atomicAdd(&lcnt[e], 1);
    __syncthreads();
    if (t < 8) lbase[t] = atomicAdd(&cursor[t], lcnt[t]);
    __syncthreads();
    int pos = off[e] + lbase[e] + rank;
    tok[pos] = n;
    gwArr[pos] = wv;
}

// ---------------- gather x rows -> packed bf16 xg (one wave per assignment row)
__global__ __launch_bounds__(256) void gather_kernel(const float* __restrict__ x, const int* __restrict__ tok,
                                                     unsigned short* __restrict__ xg) {
    int wid = threadIdx.x >> 6, lane = threadIdx.x & 63;
    int row = blockIdx.x * 4 + wid;
    int n = tok[row];
    const float4* src = (const float4*)(x + (size_t)n * C_DIM);
    ushort4* dst = (ushort4*)(xg + (size_t)row * C_DIM);
#pragma unroll
    for (int j = 0; j < 4; j++) {
        float4 v = src[lane + 64 * j];
        ushort4 o;
        o.x = f2bf(v.x); o.y = f2bf(v.y); o.z = f2bf(v.z); o.w = f2bf(v.w);
        dst[lane + 64 * j] = o;
    }
}

// ---------------- grouped GEMM, 256x256 tile, BK=32, 8 waves (2Mx4N)
// 4-buffer LDS ring + m201-style phase schedule: per BK=32 tile, TWO phases of
// {ds_read (8 or 4 b128) ; 2 global_load_lds ; s_barrier ; setprio1 + 16 MFMA +
// setprio0 ; s_barrier}. Counted vmcnt once per tile (in P1): main loop
// vmcnt(8) = (t+2)'s 4 + (t+3)'s 4 in flight; peeled tail 4 -> 0. Never drains
// in steady state. Flat dynamic work list: block wi decodes (expert, mblk, y)
// from ceil(cnt[e]/256) prefix -> perfect balance (no expert-XCD binding).
// LDS: 128B lines = row-pairs, chunk ^= (line&7) swizzle on SOURCE and READ.
// EPI=0: hs = bf16(silu(acc)); EPI=1: atomicAdd(out[tok*C+c], gw*acc)
#define VM_WAIT(S) do { __builtin_amdgcn_sched_barrier(0);                   \
    asm volatile(S ::: "memory");                                            \
    __builtin_amdgcn_sched_barrier(0); } while (0)

#define TILE_STEP(BB, SA, SB, WAITOP)                                        \
    {                                                                        \
        const unsigned short* Ab = &smem[(BB)];                              \
        short8 aa[4], bb4[4];                                                \
        _Pragma("unroll")                                                    \
        for (int m = 0; m < 4; m++) aa[m] = *(const short8*)&Ab[offA[m]];    \
        _Pragma("unroll")                                                    \
        for (int n = 0; n < 4; n++) bb4[n] = *(const short8*)&Ab[offB[n]];   \
        SA;                                                                  \
        __builtin_amdgcn_s_barrier();                                        \
        __builtin_amdgcn_sched_barrier(0);                                   \
        __builtin_amdgcn_s_setprio(1);                                       \
        _Pragma("unroll")                                                    \
        for (int m = 0; m < 4; m++)                                          \
            _Pragma("unroll")                                                \
            for (int n = 0; n < 4; n++)                                      \
                acc[m][n] = __builtin_amdgcn_mfma_f32_16x16x32_bf16(aa[m], bb4[n], acc[m][n], 0, 0, 0); \
        __builtin_amdgcn_s_setprio(0);                                       \
        __builtin_amdgcn_s_barrier();                                        \
        __builtin_amdgcn_sched_barrier(0);                                   \
        _Pragma("unroll")                                                    \
        for (int m = 0; m < 4; m++) aa[m] = *(const short8*)&Ab[offA[4 + m]];\
        SB;                                                                  \
        WAITOP;                                                              \
        __builtin_amdgcn_s_barrier();                                        \
        __builtin_amdgcn_sched_barrier(0);                                   \
        __builtin_amdgcn_s_setprio(1);                                       \
        _Pragma("unroll")                                                    \
        for (int m = 0; m < 4; m++)                                          \
            _Pragma("unroll")                                                \
            for (int n = 0; n < 4; n++)                                      \
                acc[4 + m][n] = __builtin_amdgcn_mfma_f32_16x16x32_bf16(aa[m], bb4[n], acc[4 + m][n], 0, 0, 0); \
        __builtin_amdgcn_s_setprio(0);                                       \
        __builtin_amdgcn_s_barrier();                                        \
        __builtin_amdgcn_sched_barrier(0);                                   \
    }

template <int EPI>
__global__ __launch_bounds__(512, 2) void moe_gemm_kernel(
    const unsigned short* __restrict__ A, int ldA,
    const unsigned short* __restrict__ Bt, int ldB, int bRowOff, int bColOff,
    int K, int NY,
    const int* __restrict__ cnt, const int* __restrict__ off,
    const int* __restrict__ tok, const float* __restrict__ gwArr,
    unsigned short* __restrict__ hs, int ldH,
    float* __restrict__ out) {
    __shared__ unsigned short smem[65536];   // 4 bufs x (A 8192 + B 8192 shorts) = 128 KiB

    // flat balanced work decode: wi -> (e, mblk, y), mb-inner for B-tile reuse
    int wi = blockIdx.x;
    int base = 0, e = -1, enb = 0, local = 0;
#pragma unroll
    for (int i = 0; i < 8; i++) {
        int nb = (cnt[i] + 255) >> 8;
        int sz = nb * NY;
        if (e < 0 && wi < base + sz) { e = i; enb = nb; local = wi - base; }
        base += sz;
    }
    if (e < 0) return;
    int y = local / enb;
    int mblk = local - y * enb;
    int M = cnt[e];
    int m0 = mblk * 256;
    int baseRow = off[e];
    int n0 = y * 256;

    int tid = threadIdx.x;
    int lane = tid & 63;
    int wid = tid >> 6;
    int wm = (wid >> 2) * 128;
    int wn = (wid & 3) * 64;

    f32x4 acc[8][4];
#pragma unroll
    for (int i = 0; i < 8; i++)
#pragma unroll
        for (int j = 0; j < 4; j++) acc[i][j] = (f32x4)0.f;

    const unsigned short* Bex = Bt + (size_t)e * (size_t)(C_DIM * H_DIM);

    // stage pointers: per thread 2 A-chunks + 2 B-chunks (16B each) per tile
    const unsigned short* srcA[2];
    const unsigned short* srcB[2];
    int ldsOff[2];
#pragma unroll
    for (int i = 0; i < 2; i++) {
        int c = i * 512 + tid;
        int rl = c >> 3, cl = c & 7;
        int cls = cl ^ (rl & 7);              // inverse swizzle on source
        int row = (rl << 1) | (cls >> 2);
        int kc = cls & 3;
        int rg = m0 + row; if (rg > M - 1) rg = M - 1;
        srcA[i] = A + (size_t)(baseRow + rg) * ldA + kc * 8;
        srcB[i] = Bex + (size_t)(bRowOff + n0 + row) * ldB + bColOff + kc * 8;
        ldsOff[i] = (c & ~63) * 8;            // shorts; wave-uniform base, lane*16B implicit
    }
    auto STAGE_A = [&](int buf) {
        int bbase = buf * 16384;
        GLDS16(srcA[0], &smem[bbase + ldsOff[0]]);
        GLDS16(srcA[1], &smem[bbase + ldsOff[1]]);
        srcA[0] += 32; srcA[1] += 32;         // advance k by BK=32
    };
    auto STAGE_B = [&](int buf) {
        int bbase = buf * 16384 + 8192;
        GLDS16(srcB[0], &smem[bbase + ldsOff[0]]);
        GLDS16(srcB[1], &smem[bbase + ldsOff[1]]);
        srcB[0] += 32; srcB[1] += 32;
    };

    // swizzled read offsets (shorts): row r, k-quarter kq -> line r>>1, chunk ^ (line&7)
    int kq = lane >> 4;
    int rsub = lane & 15;
    int offA[8], offB[4];
#pragma unroll
    for (int m = 0; m < 8; m++) {
        int r = wm + m * 16 + rsub;
        int rl = r >> 1;
        int cls = (((r & 1) << 2) | kq) ^ (rl & 7);
        offA[m] = rl * 64 + cls * 8;
    }
#pragma unroll
    for (int n = 0; n < 4; n++) {
        int r = wn + n * 16 + rsub;
        int rl = r >> 1;
        int cls = (((r & 1) << 2) | kq) ^ (rl & 7);
        offB[n] = 8192 + rl * 64 + cls * 8;
    }

    int nt = K >> 5;
    // prologue: tiles 0,1,2 staged (12 loads/wave); drain tile0's 4 -> vmcnt(8)
    STAGE_A(0); STAGE_B(0); STAGE_A(1); STAGE_B(1); STAGE_A(2); STAGE_B(2);
    VM_WAIT("s_waitcnt vmcnt(8)");
    __builtin_amdgcn_s_barrier();
    __builtin_amdgcn_sched_barrier(0);

    int tt = 0;
#pragma unroll 1
    for (; tt < nt - 3; ++tt) {
        TILE_STEP((tt & 3) * 16384, STAGE_A((tt + 3) & 3), STAGE_B((tt + 3) & 3),
                  VM_WAIT("s_waitcnt vmcnt(8)"))
    }
    TILE_STEP((tt & 3) * 16384, ((void)0), ((void)0), VM_WAIT("s_waitcnt vmcnt(4)")); ++tt;
    TILE_STEP((tt & 3) * 16384, ((void)0), ((void)0), VM_WAIT("s_waitcnt vmcnt(0)")); ++tt;
    TILE_STEP((tt & 3) * 16384, ((void)0), ((void)0), ((void)0));

    int gRow = (lane >> 4) * 4;
    int cLane = lane & 15;
#pragma unroll
    for (int m = 0; m < 8; m++) {
#pragma unroll
        for (int j = 0; j < 4; j++) {
            int r = m0 + wm + m * 16 + gRow + j;
            if (r < M) {
                if (EPI == 0) {
#pragma unroll
                    for (int n = 0; n < 4; n++) {
                        int c = n0 + wn + n * 16 + cLane;
                        float v = acc[m][n][j];
                        float sv = v / (1.f + __expf(-v));
                        hs[(size_t)(baseRow + r) * ldH + c] = f2bf(sv);
                    }
                } else {
                    int token = tok[baseRow + r];
                    float w = gwArr[baseRow + r];
#pragma unroll
                    for (int n = 0; n < 4; n++) {
                        int c = n0 + wn + n * 16 + cLane;
                        atomicAdd(&out[(size_t)token * C_DIM + c], w * acc[m][n][j]);
                    }
                }
            }
        }
    }
}

extern "C" void kernel_launch(void* const* d_in, const int* in_sizes, int n_in,
                              void* d_out, int out_size, void* d_ws, size_t ws_size,
                              hipStream_t stream) {
    const float* x = (const float*)d_in[0];
    const float* W1 = (const float*)d_in[1];
    const float* W2 = (const float*)d_in[2];
    const float* Wr = (const float*)d_in[3];
    float* out = (float*)d_out;

    char* p = (char*)d_ws;
    auto alloc = [&](size_t bytes) {
        char* r = p;
        p += (bytes + 255) & ~(size_t)255;
        return r;
    };
    float* pi = (float*)alloc(8 * sizeof(float));
    int* cntA = (int*)alloc(8 * sizeof(int));
    int* cursor = (int*)alloc(8 * sizeof(int));
    int* offA = (int*)alloc(8 * sizeof(int));
    int2* idx2 = (int2*)alloc((size_t)N_TOK * sizeof(int2));
    float2* wgt2 = (float2*)alloc((size_t)N_TOK * sizeof(float2));
    int* tok = (int*)alloc((size_t)N_ASSIGN * sizeof(int));
    float* gwA = (float*)alloc((size_t)N_ASSIGN * sizeof(float));
    unsigned short* W1bT = (unsigned short*)alloc((size_t)N_EXP * C_DIM * H_DIM * 2);
    unsigned short* W2bT = (unsigned short*)alloc((size_t)N_EXP * C_DIM * H_DIM * 2);
    unsigned short* xg = (unsigned short*)alloc((size_t)N_ASSIGN * C_DIM * 2);
    size_t used = (size_t)(p - (char*)d_ws);
    size_t remain = ws_size > used ? ws_size - used : 0;
    int HC = H_DIM;
    while (HC > 384 && (size_t)N_ASSIGN * HC * 2 > remain) HC >>= 1;
    unsigned short* hs = (unsigned short*)p;

    hipMemsetAsync(d_ws, 0, 1024, stream);                                      // pi, cnt, cursor, off
    hipMemsetAsync(d_out, 0, (size_t)N_TOK * C_DIM * sizeof(float), stream);    // accumulated output

    dim3 tb(32, 32, 1);
    transpose_bf16_kernel<<<dim3(H_DIM / 32, C_DIM / 32, N_EXP), tb, 0, stream>>>(W1, W1bT, C_DIM, H_DIM);
    transpose_bf16_kernel<<<dim3(C_DIM / 32, H_DIM / 32, N_EXP), tb, 0, stream>>>(W2, W2bT, H_DIM, C_DIM);

    router_kernel<<<256, 256, 0, stream>>>(x, Wr, idx2, wgt2, pi, cntA);
    finalize_router_kernel<<<1, 64, 0, stream>>>(cntA, pi, offA, out + (size_t)N_TOK * C_DIM);
    scatter_kernel<<<N_ASSIGN / 256, 256, 0, stream>>>(idx2, wgt2, offA, cursor, tok, gwA);
    gather_kernel<<<N_ASSIGN / 4, 256, 0, stream>>>(x, tok, xg);

    // max block count: sum ceil(M_e/256) <= 16384/256 + 7 = 71 -> 72
    int nChunks = H_DIM / HC;
    for (int ci = 0; ci < nChunks; ++ci) {
        int h0 = ci * HC;
        int ny1 = HC / 256;
        // GEMM1: [M_e x C] @ W1^T[H x C] -> silu -> hs[. x HC]
        moe_gemm_kernel<0><<<dim3(72 * ny1, 1, 1), 512, 0, stream>>>(
            xg, C_DIM, W1bT, C_DIM, h0, 0, C_DIM, ny1, cntA, offA, tok, gwA, hs, HC, out);
        // GEMM2: [M_e x HC] @ W2^T[C x H] -> scaled atomic scatter into out
        moe_gemm_kernel<1><<<dim3(72 * 4, 1, 1), 512, 0, stream>>>(
            hs, HC, W2bT, H_DIM, 0, h0, HC, 4, cntA, offA, tok, gwA, hs, HC, out);
    }
}

// Round 5
// 519.422 us; speedup vs baseline: 1.0320x; 1.0320x over previous
//
#include <hip/hip_runtime.h>
#include <stdint.h>

#define N_TOK 8192
#define C_DIM 1024
#define H_DIM 3072
#define N_EXP 8
#define N_ASSIGN (N_TOK * 2)

typedef __attribute__((ext_vector_type(8))) short short8;
typedef __attribute__((ext_vector_type(4))) float f32x4;

__device__ __forceinline__ unsigned short f2bf(float f) {
    union { float f; uint32_t u; } v; v.f = f;
    uint32_t r = (v.u + 0x7FFFu + ((v.u >> 16) & 1u)) >> 16;
    return (unsigned short)r;
}

#define GLDS16(SRC, DST) __builtin_amdgcn_global_load_lds( \
    (const __attribute__((address_space(1))) void*)(SRC),  \
    (__attribute__((address_space(3))) void*)(DST), 16, 0, 0)

// ---------------- transpose + fp32->bf16 convert: out[col][row] = in[row][col], per expert (grid.z)
__global__ void transpose_bf16_kernel(const float* __restrict__ in, unsigned short* __restrict__ out,
                                      int rows, int cols) {
    __shared__ float tile[32][33];
    int e = blockIdx.z;
    const float* ip = in + (size_t)e * rows * cols;
    unsigned short* op = out + (size_t)e * rows * cols;
    int col0 = blockIdx.x * 32;
    int row0 = blockIdx.y * 32;
    int tx = threadIdx.x, ty = threadIdx.y;
    tile[ty][tx] = ip[(size_t)(row0 + ty) * cols + col0 + tx];
    __syncthreads();
    op[(size_t)(col0 + ty) * rows + row0 + tx] = f2bf(tile[tx][ty]);
}

// ---------------- router: logits = x @ Wr, softmax, top-2 (lowest-index ties), renorm; pi/cnt stats
__global__ __launch_bounds__(256) void router_kernel(const float* __restrict__ x, const float* __restrict__ Wr,
                                                     int2* __restrict__ idx2, float2* __restrict__ wgt2,
                                                     float* __restrict__ piAcc, int* __restrict__ cntAcc) {
    __shared__ float s_pi[8];
    __shared__ int s_cnt[8];
    int t = threadIdx.x;
    if (t < 8) { s_pi[t] = 0.f; s_cnt[t] = 0; }
    __syncthreads();
    int lane = t & 63;
    int wid = t >> 6;
    int gwv = blockIdx.x * 4 + wid;
    int nw = gridDim.x * 4;
    for (int n = gwv; n < N_TOK; n += nw) {
        float acc[8];
#pragma unroll
        for (int e = 0; e < 8; e++) acc[e] = 0.f;
        const float* xr = x + (size_t)n * C_DIM;
#pragma unroll
        for (int j = 0; j < 16; j++) {
            int k = lane + 64 * j;
            float xv = xr[k];
            const float4* wr4 = (const float4*)(Wr + (size_t)k * 8);
            float4 a = wr4[0], b = wr4[1];
            acc[0] += xv * a.x; acc[1] += xv * a.y; acc[2] += xv * a.z; acc[3] += xv * a.w;
            acc[4] += xv * b.x; acc[5] += xv * b.y; acc[6] += xv * b.z; acc[7] += xv * b.w;
        }
#pragma unroll
        for (int off = 1; off < 64; off <<= 1) {
#pragma unroll
            for (int e = 0; e < 8; e++) acc[e] += __shfl_xor(acc[e], off, 64);
        }
        float m = acc[0];
#pragma unroll
        for (int e = 1; e < 8; e++) m = fmaxf(m, acc[e]);
        float p[8]; float s = 0.f;
#pragma unroll
        for (int e = 0; e < 8; e++) { p[e] = __expf(acc[e] - m); s += p[e]; }
        float inv = 1.f / s;
#pragma unroll
        for (int e = 0; e < 8; e++) p[e] *= inv;
        int i0 = 0; float l0 = acc[0];
#pragma unroll
        for (int e = 1; e < 8; e++) if (acc[e] > l0) { l0 = acc[e]; i0 = e; }
        int i1 = -1; float l1 = -1e30f;
#pragma unroll
        for (int e = 0; e < 8; e++) if (e != i0 && acc[e] > l1) { l1 = acc[e]; i1 = e; }
        if (lane == 0) {
            float v0 = p[i0], v1 = p[i1];
            float rs = 1.f / (v0 + v1);
            idx2[n] = make_int2(i0, i1);
            wgt2[n] = make_float2(v0 * rs, v1 * rs);
            atomicAdd(&s_cnt[i0], 1);
            atomicAdd(&s_cnt[i1], 1);
#pragma unroll
            for (int e = 0; e < 8; e++) atomicAdd(&s_pi[e], p[e]);
        }
    }
    __syncthreads();
    if (t < 8) { atomicAdd(&piAcc[t], s_pi[t]); atomicAdd(&cntAcc[t], s_cnt[t]); }
}

// ---------------- offsets (exclusive scan of cnt) + aux loss
__global__ void finalize_router_kernel(const int* __restrict__ cnt, const float* __restrict__ pi,
                                       int* __restrict__ off, float* __restrict__ aux_out) {
    if (threadIdx.x == 0) {
        int o = 0;
        float dot = 0.f;
        for (int e = 0; e < 8; e++) {
            off[e] = o;
            o += cnt[e];
            dot += (float)cnt[e] * pi[e];
        }
        aux_out[0] = 0.01f * 8.f * dot / ((float)N_TOK * (float)N_TOK);
    }
}

// ---------------- scatter: build per-expert token/weight lists (block-aggregated cursors)
__global__ __launch_bounds__(256) void scatter_kernel(const int2* __restrict__ idx2, const float2* __restrict__ wgt2,
                                                      const int* __restrict__ off, int* __restrict__ cursor,
                                                      int* __restrict__ tok, float* __restrict__ gwArr) {
    __shared__ int lcnt[8], lbase[8];
    int t = threadIdx.x;
    if (t < 8) lcnt[t] = 0;
    __syncthreads();
    int a = blockIdx.x * 256 + t;
    int n = a >> 1, k = a & 1;
    int2 id = idx2[n];
    float2 w = wgt2[n];
    int e = k ? id.y : id.x;
    float wv = k ? w.y : w.x;
    int rank = atomicAdd(&lcnt[e], 1);
    __syncthreads();
    if (t < 8) lbase[t] = atomicAdd(&cursor[t], lcnt[t]);
    __syncthreads();
    int pos = off[e] + lbase[e] + rank;
    tok[pos] = n;
    gwArr[pos] = wv;
}

// ---------------- gather x rows -> packed bf16 xg (one wave per assignment row)
__global__ __launch_bounds__(256) void gather_kernel(const float* __restrict__ x, const int* __restrict__ tok,
                                                     unsigned short* __restrict__ xg) {
    int wid = threadIdx.x >> 6, lane = threadIdx.x & 63;
    int row = blockIdx.x * 4 + wid;
    int n = tok[row];
    const float4* src = (const float4*)(x + (size_t)n * C_DIM);
    ushort4* dst = (ushort4*)(xg + (size_t)row * C_DIM);
#pragma unroll
    for (int j = 0; j < 4; j++) {
        float4 v = src[lane + 64 * j];
        ushort4 o;
        o.x = f2bf(v.x); o.y = f2bf(v.y); o.z = f2bf(v.z); o.w = f2bf(v.w);
        dst[lane + 64 * j] = o;
    }
}

// ---------------- grouped GEMM, m97 structure: 128x128 tile, BK=64, 4 waves (2x2),
// SINGLE-buffered 32 KiB LDS -> 4-5 blocks/CU; plain stage -> syncthreads ->
// compute -> syncthreads (compiler-scheduled waits; cross-block overlap hides
// the vmcnt(0) barrier drain, per m97/m114). Flat all-real work list (no empty
// blocks), mb-inner ordering for B-panel L2 reuse.
// LDS layout per matrix: 2 k-halves of 32; each half = 64 row-pair lines of
// 128 B; chunk ^= (line&7) XOR swizzle applied to SOURCE k-offset and READ
// address (gload_lds dst linear) -> PMC-verified 0 bank conflicts.
// EPI=0: hs = bf16(silu(acc)); EPI=1: atomicAdd(out[tok*C+c], gw*acc)
template <int EPI>
__global__ __launch_bounds__(256) void moe_gemm_kernel(
    const unsigned short* __restrict__ A, int ldA,
    const unsigned short* __restrict__ Bt, int ldB, int bRowOff, int bColOff,
    int K, int NY,
    const int* __restrict__ cnt, const int* __restrict__ off,
    const int* __restrict__ tok, const float* __restrict__ gwArr,
    unsigned short* __restrict__ hs, int ldH,
    float* __restrict__ out) {
    __shared__ unsigned short As[8192];   // 16 KiB: [half(2)][line(64)][chunk(8)*8 shorts]
    __shared__ unsigned short Bs[8192];

    // flat balanced work decode: wi -> (e, mblk, y); mb-inner for B-tile reuse
    int wi = blockIdx.x;
    int base = 0, e = -1, enb = 0, local = 0;
#pragma unroll
    for (int i = 0; i < 8; i++) {
        int nb = (cnt[i] + 127) >> 7;
        int sz = nb * NY;
        if (e < 0 && wi < base + sz) { e = i; enb = nb; local = wi - base; }
        base += sz;
    }
    if (e < 0) return;
    int y = local / enb;
    int mblk = local - y * enb;
    int M = cnt[e];
    int m0 = mblk * 128;
    int baseRow = off[e];
    int n0 = y * 128;

    int tid = threadIdx.x;
    int lane = tid & 63;
    int wid = tid >> 6;
    int wm = (wid >> 1) * 64;
    int wn = (wid & 1) * 64;

    f32x4 acc[4][4];
#pragma unroll
    for (int i = 0; i < 4; i++)
#pragma unroll
        for (int j = 0; j < 4; j++) acc[i][j] = (f32x4)0.f;

    const unsigned short* Bex = Bt + (size_t)e * (size_t)(C_DIM * H_DIM);

    // staging: 1024 16B-chunks per matrix tile (128 rows x 64 k); 4 per thread.
    // chunk c: half = c>>9, w = c&511, line = w>>3, cc = w&7; swz = cc ^ (line&7);
    // row = line*2 + (swz>>2); k = half*32 + (swz&3)*8
    const unsigned short* srcA[4];
    const unsigned short* srcB[4];
    int ldsOff[4];
#pragma unroll
    for (int i = 0; i < 4; i++) {
        int c = i * 256 + tid;
        int half = c >> 9;
        int w = c & 511;
        int line = w >> 3, cc = w & 7;
        int swz = cc ^ (line & 7);
        int row = (line << 1) | (swz >> 2);
        int kOff = half * 32 + (swz & 3) * 8;
        int rg = m0 + row; if (rg > M - 1) rg = M - 1;
        srcA[i] = A + (size_t)(baseRow + rg) * ldA + kOff;
        srcB[i] = Bex + (size_t)(bRowOff + n0 + row) * ldB + bColOff + kOff;
        ldsOff[i] = (c & ~63) * 8;   // shorts; wave-uniform base + lane*16B implicit
    }

    // read offsets (shorts) for kk=0; kk=1 adds 4096. row r: line r>>1,
    // chunk (((r&1)<<2)|kq) ^ (line&7), 8 shorts per chunk
    int kq = lane >> 4;
    int rsub = lane & 15;
    int offA[4], offB[4];
#pragma unroll
    for (int m = 0; m < 4; m++) {
        int r = wm + m * 16 + rsub;
        int l = r >> 1;
        int cidx = ((((r & 1) << 2) | kq) ^ (l & 7));
        offA[m] = l * 64 + cidx * 8;
    }
#pragma unroll
    for (int n = 0; n < 4; n++) {
        int r = wn + n * 16 + rsub;
        int l = r >> 1;
        int cidx = ((((r & 1) << 2) | kq) ^ (l & 7));
        offB[n] = l * 64 + cidx * 8;
    }

    int nt = K >> 6;
#pragma unroll 1
    for (int t = 0; t < nt; ++t) {
#pragma unroll
        for (int i = 0; i < 4; i++) {
            GLDS16(srcA[i], &As[ldsOff[i]]);
            GLDS16(srcB[i], &Bs[ldsOff[i]]);
            srcA[i] += 64; srcB[i] += 64;
        }
        __syncthreads();
#pragma unroll
        for (int kk = 0; kk < 2; kk++) {
            short8 a[4], b[4];
#pragma unroll
            for (int m = 0; m < 4; m++) a[m] = *(const short8*)&As[kk * 4096 + offA[m]];
#pragma unroll
            for (int n = 0; n < 4; n++) b[n] = *(const short8*)&Bs[kk * 4096 + offB[n]];
#pragma unroll
            for (int m = 0; m < 4; m++)
#pragma unroll
                for (int n = 0; n < 4; n++)
                    acc[m][n] = __builtin_amdgcn_mfma_f32_16x16x32_bf16(a[m], b[n], acc[m][n], 0, 0, 0);
        }
        __syncthreads();
    }

    int gRow = (lane >> 4) * 4;
    int cLane = lane & 15;
#pragma unroll
    for (int m = 0; m < 4; m++) {
#pragma unroll
        for (int j = 0; j < 4; j++) {
            int r = m0 + wm + m * 16 + gRow + j;
            if (r < M) {
                if (EPI == 0) {
#pragma unroll
                    for (int n = 0; n < 4; n++) {
                        int c = n0 + wn + n * 16 + cLane;
                        float v = acc[m][n][j];
                        float sv = v / (1.f + __expf(-v));
                        hs[(size_t)(baseRow + r) * ldH + c] = f2bf(sv);
                    }
                } else {
                    int token = tok[baseRow + r];
                    float w = gwArr[baseRow + r];
#pragma unroll
                    for (int n = 0; n < 4; n++) {
                        int c = n0 + wn + n * 16 + cLane;
                        atomicAdd(&out[(size_t)token * C_DIM + c], w * acc[m][n][j]);
                    }
                }
            }
        }
    }
}

extern "C" void kernel_launch(void* const* d_in, const int* in_sizes, int n_in,
                              void* d_out, int out_size, void* d_ws, size_t ws_size,
                              hipStream_t stream) {
    const float* x = (const float*)d_in[0];
    const float* W1 = (const float*)d_in[1];
    const float* W2 = (const float*)d_in[2];
    const float* Wr = (const float*)d_in[3];
    float* out = (float*)d_out;

    char* p = (char*)d_ws;
    auto alloc = [&](size_t bytes) {
        char* r = p;
        p += (bytes + 255) & ~(size_t)255;
        return r;
    };
    float* pi = (float*)alloc(8 * sizeof(float));
    int* cntA = (int*)alloc(8 * sizeof(int));
    int* cursor = (int*)alloc(8 * sizeof(int));
    int* offA = (int*)alloc(8 * sizeof(int));
    int2* idx2 = (int2*)alloc((size_t)N_TOK * sizeof(int2));
    float2* wgt2 = (float2*)alloc((size_t)N_TOK * sizeof(float2));
    int* tok = (int*)alloc((size_t)N_ASSIGN * sizeof(int));
    float* gwA = (float*)alloc((size_t)N_ASSIGN * sizeof(float));
    unsigned short* W1bT = (unsigned short*)alloc((size_t)N_EXP * C_DIM * H_DIM * 2);
    unsigned short* W2bT = (unsigned short*)alloc((size_t)N_EXP * C_DIM * H_DIM * 2);
    unsigned short* xg = (unsigned short*)alloc((size_t)N_ASSIGN * C_DIM * 2);
    size_t used = (size_t)(p - (char*)d_ws);
    size_t remain = ws_size > used ? ws_size - used : 0;
    int HC = H_DIM;
    while (HC > 384 && (size_t)N_ASSIGN * HC * 2 > remain) HC >>= 1;
    unsigned short* hs = (unsigned short*)p;

    hipMemsetAsync(d_ws, 0, 1024, stream);                                      // pi, cnt, cursor, off
    hipMemsetAsync(d_out, 0, (size_t)N_TOK * C_DIM * sizeof(float), stream);    // accumulated output

    dim3 tb(32, 32, 1);
    transpose_bf16_kernel<<<dim3(H_DIM / 32, C_DIM / 32, N_EXP), tb, 0, stream>>>(W1, W1bT, C_DIM, H_DIM);
    transpose_bf16_kernel<<<dim3(C_DIM / 32, H_DIM / 32, N_EXP), tb, 0, stream>>>(W2, W2bT, H_DIM, C_DIM);

    router_kernel<<<256, 256, 0, stream>>>(x, Wr, idx2, wgt2, pi, cntA);
    finalize_router_kernel<<<1, 64, 0, stream>>>(cntA, pi, offA, out + (size_t)N_TOK * C_DIM);
    scatter_kernel<<<N_ASSIGN / 256, 256, 0, stream>>>(idx2, wgt2, offA, cursor, tok, gwA);
    gather_kernel<<<N_ASSIGN / 4, 256, 0, stream>>>(x, tok, xg);

    // max non-empty blocks: sum_e ceil(M_e/128) <= 16384/128 + 7 = 135
    int nChunks = H_DIM / HC;
    for (int ci = 0; ci < nChunks; ++ci) {
        int h0 = ci * HC;
        int ny1 = HC / 128;
        // GEMM1: [M_e x C] @ W1^T[H x C] -> silu -> hs[. x HC]
        moe_gemm_kernel<0><<<dim3(135 * ny1, 1, 1), 256, 0, stream>>>(
            xg, C_DIM, W1bT, C_DIM, h0, 0, C_DIM, ny1, cntA, offA, tok, gwA, hs, HC, out);
        // GEMM2: [M_e x HC] @ W2^T[C x H] -> scaled atomic scatter into out
        moe_gemm_kernel<1><<<dim3(135 * 8, 1, 1), 256, 0, stream>>>(
            hs, HC, W2bT, H_DIM, 0, h0, HC, 8, cntA, offA, tok, gwA, hs, HC, out);
    }
}

// Round 6
// 499.272 us; speedup vs baseline: 1.0737x; 1.0404x over previous
//
#include <hip/hip_runtime.h>
#include <stdint.h>

#define N_TOK 8192
#define C_DIM 1024
#define H_DIM 3072
#define N_EXP 8
#define N_ASSIGN (N_TOK * 2)

typedef __attribute__((ext_vector_type(8))) short short8;
typedef __attribute__((ext_vector_type(4))) float f32x4;

__device__ __forceinline__ unsigned short f2bf(float f) {
    union { float f; uint32_t u; } v; v.f = f;
    uint32_t r = (v.u + 0x7FFFu + ((v.u >> 16) & 1u)) >> 16;
    return (unsigned short)r;
}

#define GLDS16(SRC, DST) __builtin_amdgcn_global_load_lds( \
    (const __attribute__((address_space(1))) void*)(SRC),  \
    (__attribute__((address_space(3))) void*)(DST), 16, 0, 0)

// ---------------- transpose + fp32->bf16 convert: out[col][row] = in[row][col], per expert (grid.z)
__global__ void transpose_bf16_kernel(const float* __restrict__ in, unsigned short* __restrict__ out,
                                      int rows, int cols) {
    __shared__ float tile[32][33];
    int e = blockIdx.z;
    const float* ip = in + (size_t)e * rows * cols;
    unsigned short* op = out + (size_t)e * rows * cols;
    int col0 = blockIdx.x * 32;
    int row0 = blockIdx.y * 32;
    int tx = threadIdx.x, ty = threadIdx.y;
    tile[ty][tx] = ip[(size_t)(row0 + ty) * cols + col0 + tx];
    __syncthreads();
    op[(size_t)(col0 + ty) * rows + row0 + tx] = f2bf(tile[tx][ty]);
}

// ---------------- router: logits = x @ Wr, softmax, top-2 (lowest-index ties), renorm; pi/cnt stats
__global__ __launch_bounds__(256) void router_kernel(const float* __restrict__ x, const float* __restrict__ Wr,
                                                     int2* __restrict__ idx2, float2* __restrict__ wgt2,
                                                     float* __restrict__ piAcc, int* __restrict__ cntAcc) {
    __shared__ float s_pi[8];
    __shared__ int s_cnt[8];
    int t = threadIdx.x;
    if (t < 8) { s_pi[t] = 0.f; s_cnt[t] = 0; }
    __syncthreads();
    int lane = t & 63;
    int wid = t >> 6;
    int gwv = blockIdx.x * 4 + wid;
    int nw = gridDim.x * 4;
    for (int n = gwv; n < N_TOK; n += nw) {
        float acc[8];
#pragma unroll
        for (int e = 0; e < 8; e++) acc[e] = 0.f;
        const float* xr = x + (size_t)n * C_DIM;
#pragma unroll
        for (int j = 0; j < 16; j++) {
            int k = lane + 64 * j;
            float xv = xr[k];
            const float4* wr4 = (const float4*)(Wr + (size_t)k * 8);
            float4 a = wr4[0], b = wr4[1];
            acc[0] += xv * a.x; acc[1] += xv * a.y; acc[2] += xv * a.z; acc[3] += xv * a.w;
            acc[4] += xv * b.x; acc[5] += xv * b.y; acc[6] += xv * b.z; acc[7] += xv * b.w;
        }
#pragma unroll
        for (int off = 1; off < 64; off <<= 1) {
#pragma unroll
            for (int e = 0; e < 8; e++) acc[e] += __shfl_xor(acc[e], off, 64);
        }
        float m = acc[0];
#pragma unroll
        for (int e = 1; e < 8; e++) m = fmaxf(m, acc[e]);
        float p[8]; float s = 0.f;
#pragma unroll
        for (int e = 0; e < 8; e++) { p[e] = __expf(acc[e] - m); s += p[e]; }
        float inv = 1.f / s;
#pragma unroll
        for (int e = 0; e < 8; e++) p[e] *= inv;
        int i0 = 0; float l0 = acc[0];
#pragma unroll
        for (int e = 1; e < 8; e++) if (acc[e] > l0) { l0 = acc[e]; i0 = e; }
        int i1 = -1; float l1 = -1e30f;
#pragma unroll
        for (int e = 0; e < 8; e++) if (e != i0 && acc[e] > l1) { l1 = acc[e]; i1 = e; }
        if (lane == 0) {
            float v0 = p[i0], v1 = p[i1];
            float rs = 1.f / (v0 + v1);
            idx2[n] = make_int2(i0, i1);
            wgt2[n] = make_float2(v0 * rs, v1 * rs);
            atomicAdd(&s_cnt[i0], 1);
            atomicAdd(&s_cnt[i1], 1);
#pragma unroll
            for (int e = 0; e < 8; e++) atomicAdd(&s_pi[e], p[e]);
        }
    }
    __syncthreads();
    if (t < 8) { atomicAdd(&piAcc[t], s_pi[t]); atomicAdd(&cntAcc[t], s_cnt[t]); }
}

// ---------------- offsets (exclusive scan of cnt) + aux loss
__global__ void finalize_router_kernel(const int* __restrict__ cnt, const float* __restrict__ pi,
                                       int* __restrict__ off, float* __restrict__ aux_out) {
    if (threadIdx.x == 0) {
        int o = 0;
        float dot = 0.f;
        for (int e = 0; e < 8; e++) {
            off[e] = o;
            o += cnt[e];
            dot += (float)cnt[e] * pi[e];
        }
        aux_out[0] = 0.01f * 8.f * dot / ((float)N_TOK * (float)N_TOK);
    }
}

// ---------------- scatter: build per-expert token/weight lists (block-aggregated cursors)
__global__ __launch_bounds__(256) void scatter_kernel(const int2* __restrict__ idx2, const float2* __restrict__ wgt2,
                                                      const int* __restrict__ off, int* __restrict__ cursor,
                                                      int* __restrict__ tok, float* __restrict__ gwArr) {
    __shared__ int lcnt[8], lbase[8];
    int t = threadIdx.x;
    if (t < 8) lcnt[t] = 0;
    __syncthreads();
    int a = blockIdx.x * 256 + t;
    int n = a >> 1, k = a & 1;
    int2 id = idx2[n];
    float2 w = wgt2[n];
    int e = k ? id.y : id.x;
    float wv = k ? w.y : w.x;
    int rank = atomicAdd(&lcnt[e], 1);
    __syncthreads();
    if (t < 8) lbase[t] = atomicAdd(&cursor[t], lcnt[t]);
    __syncthreads();
    int pos = off[e] + lbase[e] + rank;
    tok[pos] = n;
    gwArr[pos] = wv;
}

// ---------------- gather x rows -> packed bf16 xg (one wave per assignment row)
__global__ __launch_bounds__(256) void gather_kernel(const float* __restrict__ x, const int* __restrict__ tok,
                                                     unsigned short* __restrict__ xg) {
    int wid = threadIdx.x >> 6, lane = threadIdx.x & 63;
    int row = blockIdx.x * 4 + wid;
    int n = tok[row];
    const float4* src = (const float4*)(x + (size_t)n * C_DIM);
    ushort4* dst = (ushort4*)(xg + (size_t)row * C_DIM);
#pragma unroll
    for (int j = 0; j < 4; j++) {
        float4 v = src[lane + 64 * j];
        ushort4 o;
        o.x = f2bf(v.x); o.y = f2bf(v.y); o.z = f2bf(v.z); o.w = f2bf(v.w);
        dst[lane + 64 * j] = o;
    }
}

// ---------------- grouped GEMM, m97 structure: 128x128 tile, BK=64, 4 waves (2x2),
// single-buffered 32 KiB LDS, plain stage -> sync -> compute -> sync.
// NEW (R5): bijective XCD-aware remap (m204): physical block p on XCD p&7 owns a
// CONTIGUOUS chunk of logical work -> blocks sharing a B-stripe (mb-inner order)
// run on ONE XCD, B-stripe stays hot in that XCD's 4 MiB L2 (fix for the 461 MB
// = ~6x L2-miss amplification measured in R4).
// LDS: 2 k-halves; 64 row-pair lines of 128 B; chunk ^= (line&7) XOR swizzle on
// SOURCE k-offset and READ address (gload_lds dst linear) -> 0 bank conflicts.
// EPI=0: hs = bf16(silu(acc)); EPI=1: atomicAdd(out[tok*C+c], gw*acc)
template <int EPI>
__global__ __launch_bounds__(256) void moe_gemm_kernel(
    const unsigned short* __restrict__ A, int ldA,
    const unsigned short* __restrict__ Bt, int ldB, int bRowOff, int bColOff,
    int K, int NY,
    const int* __restrict__ cnt, const int* __restrict__ off,
    const int* __restrict__ tok, const float* __restrict__ gwArr,
    unsigned short* __restrict__ hs, int ldH,
    float* __restrict__ out) {
    __shared__ unsigned short As[8192];   // 16 KiB: [half(2)][line(64)][chunk(8)*8 shorts]
    __shared__ unsigned short Bs[8192];

    // ---- total logical work + per-expert block counts
    int nbs[8];
    int tot = 0;
#pragma unroll
    for (int i = 0; i < 8; i++) {
        nbs[i] = (cnt[i] + 127) >> 7;
        tot += nbs[i] * NY;
    }
    // ---- bijective physical->logical XCD remap (m204)
    int p = blockIdx.x;
    int q = tot >> 3, r = tot & 7;
    int x = p & 7, s = p >> 3;
    int capx = (x < r) ? q + 1 : q;
    if (s >= capx) return;
    int wi = (x < r) ? x * (q + 1) + s : r * (q + 1) + (x - r) * q + s;

    // ---- decode wi -> (e, mblk, y); mb-inner for B-stripe reuse
    int base = 0, e = -1, enb = 0, local = 0;
#pragma unroll
    for (int i = 0; i < 8; i++) {
        int sz = nbs[i] * NY;
        if (e < 0 && wi < base + sz) { e = i; enb = nbs[i]; local = wi - base; }
        base += sz;
    }
    if (e < 0) return;
    int y = local / enb;
    int mblk = local - y * enb;
    int M = cnt[e];
    int m0 = mblk * 128;
    int baseRow = off[e];
    int n0 = y * 128;

    int tid = threadIdx.x;
    int lane = tid & 63;
    int wid = tid >> 6;
    int wm = (wid >> 1) * 64;
    int wn = (wid & 1) * 64;

    f32x4 acc[4][4];
#pragma unroll
    for (int i = 0; i < 4; i++)
#pragma unroll
        for (int j = 0; j < 4; j++) acc[i][j] = (f32x4)0.f;

    const unsigned short* Bex = Bt + (size_t)e * (size_t)(C_DIM * H_DIM);

    // staging: 1024 16B-chunks per matrix tile (128 rows x 64 k); 4 per thread.
    const unsigned short* srcA[4];
    const unsigned short* srcB[4];
    int ldsOff[4];
#pragma unroll
    for (int i = 0; i < 4; i++) {
        int c = i * 256 + tid;
        int half = c >> 9;
        int w = c & 511;
        int line = w >> 3, cc = w & 7;
        int swz = cc ^ (line & 7);
        int row = (line << 1) | (swz >> 2);
        int kOff = half * 32 + (swz & 3) * 8;
        int rg = m0 + row; if (rg > M - 1) rg = M - 1;
        srcA[i] = A + (size_t)(baseRow + rg) * ldA + kOff;
        srcB[i] = Bex + (size_t)(bRowOff + n0 + row) * ldB + bColOff + kOff;
        ldsOff[i] = (c & ~63) * 8;   // shorts; wave-uniform base + lane*16B implicit
    }

    // read offsets (shorts) for kk=0; kk=1 adds 4096.
    int kq = lane >> 4;
    int rsub = lane & 15;
    int offA[4], offB[4];
#pragma unroll
    for (int m = 0; m < 4; m++) {
        int rr = wm + m * 16 + rsub;
        int l = rr >> 1;
        int cidx = ((((rr & 1) << 2) | kq) ^ (l & 7));
        offA[m] = l * 64 + cidx * 8;
    }
#pragma unroll
    for (int n = 0; n < 4; n++) {
        int rr = wn + n * 16 + rsub;
        int l = rr >> 1;
        int cidx = ((((rr & 1) << 2) | kq) ^ (l & 7));
        offB[n] = l * 64 + cidx * 8;
    }

    int nt = K >> 6;
#pragma unroll 1
    for (int t = 0; t < nt; ++t) {
#pragma unroll
        for (int i = 0; i < 4; i++) {
            GLDS16(srcA[i], &As[ldsOff[i]]);
            GLDS16(srcB[i], &Bs[ldsOff[i]]);
            srcA[i] += 64; srcB[i] += 64;
        }
        __syncthreads();
#pragma unroll
        for (int kk = 0; kk < 2; kk++) {
            short8 a[4], b[4];
#pragma unroll
            for (int m = 0; m < 4; m++) a[m] = *(const short8*)&As[kk * 4096 + offA[m]];
#pragma unroll
            for (int n = 0; n < 4; n++) b[n] = *(const short8*)&Bs[kk * 4096 + offB[n]];
#pragma unroll
            for (int m = 0; m < 4; m++)
#pragma unroll
                for (int n = 0; n < 4; n++)
                    acc[m][n] = __builtin_amdgcn_mfma_f32_16x16x32_bf16(a[m], b[n], acc[m][n], 0, 0, 0);
        }
        __syncthreads();
    }

    int gRow = (lane >> 4) * 4;
    int cLane = lane & 15;
#pragma unroll
    for (int m = 0; m < 4; m++) {
#pragma unroll
        for (int j = 0; j < 4; j++) {
            int rr = m0 + wm + m * 16 + gRow + j;
            if (rr < M) {
                if (EPI == 0) {
#pragma unroll
                    for (int n = 0; n < 4; n++) {
                        int c = n0 + wn + n * 16 + cLane;
                        float v = acc[m][n][j];
                        float sv = v / (1.f + __expf(-v));
                        hs[(size_t)(baseRow + rr) * ldH + c] = f2bf(sv);
                    }
                } else {
                    int token = tok[baseRow + rr];
                    float w = gwArr[baseRow + rr];
#pragma unroll
                    for (int n = 0; n < 4; n++) {
                        int c = n0 + wn + n * 16 + cLane;
                        atomicAdd(&out[(size_t)token * C_DIM + c], w * acc[m][n][j]);
                    }
                }
            }
        }
    }
}

extern "C" void kernel_launch(void* const* d_in, const int* in_sizes, int n_in,
                              void* d_out, int out_size, void* d_ws, size_t ws_size,
                              hipStream_t stream) {
    const float* x = (const float*)d_in[0];
    const float* W1 = (const float*)d_in[1];
    const float* W2 = (const float*)d_in[2];
    const float* Wr = (const float*)d_in[3];
    float* out = (float*)d_out;

    char* p = (char*)d_ws;
    auto alloc = [&](size_t bytes) {
        char* r = p;
        p += (bytes + 255) & ~(size_t)255;
        return r;
    };
    float* pi = (float*)alloc(8 * sizeof(float));
    int* cntA = (int*)alloc(8 * sizeof(int));
    int* cursor = (int*)alloc(8 * sizeof(int));
    int* offA = (int*)alloc(8 * sizeof(int));
    int2* idx2 = (int2*)alloc((size_t)N_TOK * sizeof(int2));
    float2* wgt2 = (float2*)alloc((size_t)N_TOK * sizeof(float2));
    int* tok = (int*)alloc((size_t)N_ASSIGN * sizeof(int));
    float* gwA = (float*)alloc((size_t)N_ASSIGN * sizeof(float));
    unsigned short* W1bT = (unsigned short*)alloc((size_t)N_EXP * C_DIM * H_DIM * 2);
    unsigned short* W2bT = (unsigned short*)alloc((size_t)N_EXP * C_DIM * H_DIM * 2);
    unsigned short* xg = (unsigned short*)alloc((size_t)N_ASSIGN * C_DIM * 2);
    size_t used = (size_t)(p - (char*)d_ws);
    size_t remain = ws_size > used ? ws_size - used : 0;
    int HC = H_DIM;
    while (HC > 384 && (size_t)N_ASSIGN * HC * 2 > remain) HC >>= 1;
    unsigned short* hs = (unsigned short*)p;

    hipMemsetAsync(d_ws, 0, 1024, stream);                                      // pi, cnt, cursor, off
    hipMemsetAsync(d_out, 0, (size_t)N_TOK * C_DIM * sizeof(float), stream);    // accumulated output

    dim3 tb(32, 32, 1);
    transpose_bf16_kernel<<<dim3(H_DIM / 32, C_DIM / 32, N_EXP), tb, 0, stream>>>(W1, W1bT, C_DIM, H_DIM);
    transpose_bf16_kernel<<<dim3(C_DIM / 32, H_DIM / 32, N_EXP), tb, 0, stream>>>(W2, W2bT, H_DIM, C_DIM);

    router_kernel<<<256, 256, 0, stream>>>(x, Wr, idx2, wgt2, pi, cntA);
    finalize_router_kernel<<<1, 64, 0, stream>>>(cntA, pi, offA, out + (size_t)N_TOK * C_DIM);
    scatter_kernel<<<N_ASSIGN / 256, 256, 0, stream>>>(idx2, wgt2, offA, cursor, tok, gwA);
    gather_kernel<<<N_ASSIGN / 4, 256, 0, stream>>>(x, tok, xg);

    // max non-empty logical blocks: sum_e ceil(M_e/128) <= 16384/128 + 7 = 135;
    // +8 physical padding so every XCD's quota (q+1) is covered by the remap.
    int nChunks = H_DIM / HC;
    for (int ci = 0; ci < nChunks; ++ci) {
        int h0 = ci * HC;
        int ny1 = HC / 128;
        // GEMM1: [M_e x C] @ W1^T[H x C] -> silu -> hs[. x HC]
        moe_gemm_kernel<0><<<dim3(135 * ny1 + 8, 1, 1), 256, 0, stream>>>(
            xg, C_DIM, W1bT, C_DIM, h0, 0, C_DIM, ny1, cntA, offA, tok, gwA, hs, HC, out);
        // GEMM2: [M_e x HC] @ W2^T[C x H] -> scaled atomic scatter into out
        moe_gemm_kernel<1><<<dim3(135 * 8 + 8, 1, 1), 256, 0, stream>>>(
            hs, HC, W2bT, H_DIM, 0, h0, HC, 8, cntA, offA, tok, gwA, hs, HC, out);
    }
}